// Round 1
// 67.608 us; speedup vs baseline: 1.0552x; 1.0552x over previous
//
#include <hip/hip_runtime.h>
#include <math.h>

// single_channel_interp (B=8, D=64, T=512, O=256) — R6
// R5 was exp2-issue-bound: ~368 v_exp_f32/thread (2 per (t,o) pair).
// R6 exploits the UNIFORM interpolation grid: for fixed t,
//   P(t,o) = 2^(u_t + w_t*g_o) obeys P(t,o+D) = P(t,o) * 2^(w_t*D*h),
// an exact geometric recurrence (per-t constant ratio). The per-o factor
// 2^(cc_o) (cc=-a2*g^2) cancels in y=SUM(Pv)/SUM(P) and both transformed
// outputs, and adds analytically (+cc*ln2) to the logsumexp output.
// Power-10 chain: Q = P^10 by squaring; its ratio rho^10 precomputed.
// => 1 exp2 per (t, 256 o's) in the hot loop + 2 exp2/t at staging,
//    and 3 packed f32 ops per (t,o). ~180x fewer transcendentals.
// Lane owns o in {lane, lane+64, lane+128, lane+192} (stride-64 runs so
// partial writes/reads stay contiguous-per-lane); wave wv owns t-chunk wv.

namespace {
constexpr int kB = 8, kD = 64, kT = 512, kO = 256;
constexpr int kTH = 512;          // 8 waves
constexpr float kLOG2E = 1.4426950408889634f;
constexpr float kLN2   = 0.6931471805599453f;
}

typedef float f2 __attribute__((ext_vector_type(2)));

__global__ __launch_bounds__(kTH, 4) void interp_kernel(
    const float* __restrict__ x,     // (B, 3D, T)
    const float* __restrict__ grid,  // (B, O)
    const float* __restrict__ kern,  // (D,)
    float* __restrict__ out)         // (B, 3D, O)
{
    // Staging: float4 (u, w, rho, rho10) per compacted t in [0, 2048) floats,
    //          v per t in [2048, 2560).
    // Epilogue reuse: partials [8 waves][256 o] float4 (L, Y, Q, Z) = 8192 floats.
    __shared__ __align__(16) float smem[8192 + 8];
    float* s_v   = smem + 2048;
    float* s_cnt = smem + 8192;      // 8 per-wave live counts

    const int tid  = threadIdx.x;
    const int lane = tid & 63;
    const int wv   = tid >> 6;       // 0..7 = t-chunk owner

    const int bd = blockIdx.x;
    const int b  = bd >> 6;
    const int d  = bd & (kD - 1);

    const float* base = x + (size_t)b * (3 * kD * kT);
    const float* Vrow = base + (size_t)d * kT;
    const float* Mrow = base + (size_t)(kD + d) * kT;
    const float* Trow = base + (size_t)(2 * kD + d) * kT;

    const float k     = kern[d];
    const float alpha = fmaxf(k, 0.0f) + log1pf(expf(-fabsf(k)));
    const float a2    = alpha * kLOG2E;

    const float* gB  = grid + b * kO;
    const float h64  = (gB[kO - 1] - gB[0]) * (64.0f / 255.0f);  // o-step of 64

    // ---- Stage + compact (thread i <-> t=i, coalesced loads) ----
    const float tt = Trow[tid];
    const float mm = Mrow[tid];
    const float vv = Vrow[tid];
    const bool keep = (mm != 0.0f);
    const unsigned long long ball = __ballot(keep);
    if (lane == 0) s_cnt[wv] = (float)__popcll(ball);
    __syncthreads();

    int bsum = 0, total = 0;
    #pragma unroll
    for (int j = 0; j < 8; ++j) {
        const int c = (int)s_cnt[j];
        bsum  += (j < wv) ? c : 0;
        total += c;
    }
    const int padded = (total + 31) & ~31;           // chunk multiple of 4

    if (keep) {
        const int pos = bsum + __popcll(ball & ((1ull << lane) - 1ull));
        const float u  = -a2 * tt * tt;              // live => mask==1 => logm=0
        const float w  = 2.0f * a2 * tt;
        const float wh = w * h64;
        ((float4*)smem)[pos] = make_float4(u, w,
            __builtin_amdgcn_exp2f(wh),              // rho   (power-1 chain)
            __builtin_amdgcn_exp2f(10.0f * wh));     // rho10 (power-10 chain)
        s_v[pos] = vv;
    }
    if (tid >= total && tid < padded) {              // neutral padding: P=0
        ((float4*)smem)[tid] = make_float4(-500.0f, 0.0f, 1.0f, 1.0f);
        s_v[tid] = 0.0f;
    }
    __syncthreads();

    const float g0 = gB[lane];                       // o0 = lane

    f2 aL0 = {0.f, 0.f}, aY0 = {0.f, 0.f};
    f2 aL1 = {0.f, 0.f}, aY1 = {0.f, 0.f};
    f2 aL2 = {0.f, 0.f}, aY2 = {0.f, 0.f};
    f2 aL3 = {0.f, 0.f}, aY3 = {0.f, 0.f};

    const int chunk = padded >> 3;                   // multiple of 4
    const int t0 = wv * chunk;
    for (int t = t0; t < t0 + chunk; t += 4) {
        #pragma unroll
        for (int ss = 0; ss < 4; ++ss) {
            // Broadcast LDS reads (all 64 lanes same address): conflict-free.
            const float4 f = ((const float4*)smem)[t + ss];
            const float  va = s_v[t + ss];
            const float a0 = fmaf(f.y, g0, f.x);     // u + w*g(lane)
            const float P  = __builtin_amdgcn_exp2f(a0);
            const float P2 = P * P, P4 = P2 * P2, P8 = P4 * P4;
            f2 pq;  pq.x  = P;    pq.y  = P8 * P2;   // {P, P^10}
            f2 rho; rho.x = f.z;  rho.y = f.w;       // {rho, rho^10}
            f2 vva; vva.x = va;   vva.y = va;
            aL0 += pq; aY0 += pq * vva; pq *= rho;   // o = lane
            aL1 += pq; aY1 += pq * vva; pq *= rho;   // o = lane + 64
            aL2 += pq; aY2 += pq * vva; pq *= rho;   // o = lane + 128
            aL3 += pq; aY3 += pq * vva;              // o = lane + 192
        }
    }

    // ---- Combine the 8 t-chunks through LDS ----
    __syncthreads();                                 // staging reads all done
    float4* part = (float4*)smem;                    // [8][256] = (L, Y, Q, Z)
    part[wv * kO + lane      ] = make_float4(aL0.x, aY0.x, aL0.y, aY0.y);
    part[wv * kO + lane +  64] = make_float4(aL1.x, aY1.x, aL1.y, aY1.y);
    part[wv * kO + lane + 128] = make_float4(aL2.x, aY2.x, aL2.y, aY2.y);
    part[wv * kO + lane + 192] = make_float4(aL3.x, aY3.x, aL3.y, aY3.y);
    __syncthreads();

    const int o     = tid & 255;
    const int which = tid >> 8;                      // 0: (L,Y)  1: (Q,Z)
    const float* pb = smem + o * 4 + which * 2;
    f2 s2 = {0.f, 0.f};
    #pragma unroll
    for (int j = 0; j < 8; ++j) {
        const f2 p = *(const f2*)(pb + j * 1024);
        s2 += p;
    }

    float* ob = out + (size_t)b * (3 * kD * kO);
    if (which == 0) {
        const float L = s2.x, Y = s2.y;
        const float gv = gB[o];
        ob[(size_t)d * kO + o] = Y / L;
        // real L = 2^cc * Ltilde, cc = -a2*g^2  =>  ln L = (log2(Lt) + cc)*ln2
        ob[(size_t)(kD + d) * kO + o] =
            (__builtin_amdgcn_logf(L) - a2 * gv * gv) * kLN2;
    } else {
        ob[(size_t)(2 * kD + d) * kO + o] = s2.y / s2.x;
    }
}

extern "C" void kernel_launch(void* const* d_in, const int* in_sizes, int n_in,
                              void* d_out, int out_size, void* d_ws, size_t ws_size,
                              hipStream_t stream) {
    const float* x    = (const float*)d_in[0];
    const float* grid = (const float*)d_in[1];
    const float* kern = (const float*)d_in[2];
    float* out        = (float*)d_out;
    interp_kernel<<<dim3(kB * kD), dim3(kTH), 0, stream>>>(x, grid, kern, out);
}